// Round 5
// baseline (518.887 us; speedup 1.0000x reference)
//
#include <hip/hip_runtime.h>

#define B_ 32
#define T_ 4096
#define D_ 64
#define H_ 128
#define S_ 64
#define BTS (B_*T_*S_)   /* 8388608 */

#define NCH 32      /* chunks per sequence */
#define CL  128     /* chunk length */

// workspace float offsets
#define EM_OFF    0
#define BETA_OFF  BTS
#define P_OFF     (2*BTS)
#define PT_OFF    (2*BTS + 4096)
#define INITP_OFF (2*BTS + 8192)
// output float offsets
#define SP_OFF   0
#define MARG_OFF BTS
#define DUR_OFF  (BTS + 2048)
#define LL_OFF   (BTS + 2112)

__device__ __forceinline__ float wsum(float v) {
    #pragma unroll
    for (int m = 1; m < 64; m <<= 1) v += __shfl_xor(v, m, 64);
    return v;
}
__device__ __forceinline__ float wmax(float v) {
    #pragma unroll
    for (int m = 1; m < 64; m <<= 1) v = fmaxf(v, __shfl_xor(v, m, 64));
    return v;
}
__device__ __forceinline__ float rlane(float v, int k) {
    return __int_as_float(__builtin_amdgcn_readlane(__float_as_int(v), k));
}
// DPP wave64 sum: VALU-only (no lgkmcnt), result complete in lane 63.
template<int CTRL, int RM>
__device__ __forceinline__ float dppadd(float v) {
    return v + __int_as_float(__builtin_amdgcn_update_dpp(
        0, __float_as_int(v), CTRL, RM, 0xf, false));
}
__device__ __forceinline__ float wsum_dpp63(float v) {
    v = dppadd<0x111, 0xf>(v);   // row_shr:1
    v = dppadd<0x112, 0xf>(v);   // row_shr:2
    v = dppadd<0x114, 0xf>(v);   // row_shr:4
    v = dppadd<0x118, 0xf>(v);   // row_shr:8
    v = dppadd<0x142, 0xa>(v);   // row_bcast15
    v = dppadd<0x143, 0xc>(v);   // row_bcast31 -> lane63 = total
    return v;
}

// ---------------- Kernel A: prep (trans probs, init probs, durations, zero marginals+ll)
__global__ __launch_bounds__(256) void prep_k(const float* __restrict__ LT,
                                              const float* __restrict__ lip,
                                              const float* __restrict__ logr,
                                              const float* __restrict__ logitp,
                                              float* __restrict__ ws,
                                              float* __restrict__ out) {
    int tid = threadIdx.x, wid = tid >> 6, lane = tid & 63;
    for (int r = wid; r < S_; r += 4) {
        float x = (lane == r) ? -1e10f : LT[r * S_ + lane];
        float m = wmax(x);
        float e = __expf(x - m);
        float s = wsum(e);
        float p = e / s + 1e-10f;
        ws[P_OFF  + r * S_ + lane] = p;
        ws[PT_OFF + lane * S_ + r] = p;
    }
    if (wid == 0) {
        float x = lip[lane];
        float m = wmax(x);
        float e = __expf(x - m);
        float s = wsum(e);
        ws[INITP_OFF + lane] = e / s;
    } else if (wid == 1) {
        float r = __expf(logr[lane]);
        float p = 1.f / (1.f + __expf(-logitp[lane]));
        out[DUR_OFF + lane] = r * (1.f - p) / p;
    }
    for (int i = tid; i < B_ * S_; i += 256) out[MARG_OFF + i] = 0.f;
    if (tid < B_) out[LL_OFF + tid] = 0.f;   // ll accumulated via atomicAdd
}

// ---------------- Kernel B: emission MLP + softmax -> em (B,T,S) fp32
// Zero-LDS: each wave owns 8 rows; all activation broadcasts via v_readlane
// (register-resident operands, VALU-pipe) instead of LDS-broadcast reads.
__global__ __launch_bounds__(256) void mlp_k(const float* __restrict__ obs,
                                             const float* __restrict__ W1, const float* __restrict__ b1,
                                             const float* __restrict__ W2, const float* __restrict__ b2,
                                             const float* __restrict__ W3, const float* __restrict__ b3,
                                             float* __restrict__ em) {
    int tid = threadIdx.x, wid = tid >> 6, lane = tid & 63;
    const float2* W1v = (const float2*)W1;
    const float2* W2v = (const float2*)W2;
    float2 b1v = ((const float2*)b1)[lane];
    float2 b2v = ((const float2*)b2)[lane];
    float  b3v = b3[lane];

    int gw = blockIdx.x * 4 + wid;            // global wave id
    for (int c = gw; c < (B_ * T_) / 8; c += gridDim.x * 4) {
        int r0 = c * 8;
        // ---- load 8 rows: v[i][lane] = obs[r0+i][lane] ----
        float v[8];
        #pragma unroll
        for (int i = 0; i < 8; i++)
            v[i] = obs[(size_t)(r0 + i) * D_ + lane];

        // ---- layer 1: h[j] = relu(sum_d x[d]*W1[d][j]), j = 2*lane+{0,1} ----
        float hx[8] = {0,0,0,0,0,0,0,0};
        float hy[8] = {0,0,0,0,0,0,0,0};
        #pragma unroll 4
        for (int d = 0; d < D_; d++) {
            float2 w = W1v[d * 64 + lane];
            #pragma unroll
            for (int i = 0; i < 8; i++) {
                float xs = rlane(v[i], d);
                hx[i] = fmaf(xs, w.x, hx[i]);
                hy[i] = fmaf(xs, w.y, hy[i]);
            }
        }
        #pragma unroll
        for (int i = 0; i < 8; i++) {
            hx[i] = fmaxf(hx[i] + b1v.x, 0.f);
            hy[i] = fmaxf(hy[i] + b1v.y, 0.f);
        }

        // ---- layer 2: h1[2L] lives in hx[*]@lane L, h1[2L+1] in hy[*]@lane L ----
        float gx[8] = {0,0,0,0,0,0,0,0};
        float gy[8] = {0,0,0,0,0,0,0,0};
        #pragma unroll 2
        for (int L = 0; L < 64; L++) {
            float2 wa = W2v[(2 * L    ) * 64 + lane];
            float2 wb = W2v[(2 * L + 1) * 64 + lane];
            #pragma unroll
            for (int i = 0; i < 8; i++) {
                float ha = rlane(hx[i], L);
                float hb = rlane(hy[i], L);
                gx[i] = fmaf(ha, wa.x, gx[i]); gy[i] = fmaf(ha, wa.y, gy[i]);
                gx[i] = fmaf(hb, wb.x, gx[i]); gy[i] = fmaf(hb, wb.y, gy[i]);
            }
        }
        #pragma unroll
        for (int i = 0; i < 8; i++) {
            gx[i] = fmaxf(gx[i] + b2v.x, 0.f);
            gy[i] = fmaxf(gy[i] + b2v.y, 0.f);
        }

        // ---- layer 3: logits[s] = sum_k h2[k]*W3[k][s], s = lane ----
        float l[8] = {0,0,0,0,0,0,0,0};
        #pragma unroll 2
        for (int L = 0; L < 64; L++) {
            float wa = W3[(2 * L    ) * 64 + lane];
            float wb = W3[(2 * L + 1) * 64 + lane];
            #pragma unroll
            for (int i = 0; i < 8; i++) {
                l[i] = fmaf(rlane(gx[i], L), wa, l[i]);
                l[i] = fmaf(rlane(gy[i], L), wb, l[i]);
            }
        }
        // ---- softmax per row across lanes + store ----
        #pragma unroll
        for (int i = 0; i < 8; i++) {
            float li = l[i] + b3v;
            float m = wmax(li);
            float e = __expf(li - m);
            float s = wsum(e);
            em[(size_t)(r0 + i) * S_ + lane] = e * __builtin_amdgcn_rcpf(s);
        }
    }
}

// ---------------- Kernel C: chunked fwd/bwd recursions, 4 waves per chain.
// T split into NCH chunks of CL; 32 warm-up steps from a proxy start
// (projective contraction of diag(e)·M forgets the start vector), then CL
// exact steps. Per-chunk sum(log S_t) atomicAdd'd to ll.
__global__ __launch_bounds__(256) void scan_k(const float* __restrict__ em,
                                              const float* __restrict__ Pm,
                                              const float* __restrict__ PTm,
                                              const float* __restrict__ initp,
                                              float* __restrict__ alpha,   // d_out SP region
                                              float* __restrict__ beta,    // ws
                                              float* __restrict__ ll) {
    __shared__ float part[2][4][64];
    int blk = blockIdx.x, tid = threadIdx.x;
    int lane = tid & 63;
    int w = tid >> 6;
    int kbase = __builtin_amdgcn_readfirstlane(w << 4);
    bool isf = blk < B_ * NCH;
    int lin  = isf ? blk : blk - B_ * NCH;
    int b  = lin / NCH;
    int ch = lin % NCH;
    const float* M = isf ? PTm : Pm;
    float pt[16];
    #pragma unroll
    for (int i = 0; i < 4; i++) {
        float4 v = ((const float4*)(M + lane * 64 + kbase))[i];
        pt[4*i] = v.x; pt[4*i+1] = v.y; pt[4*i+2] = v.z; pt[4*i+3] = v.w;
    }
    const float* emb = em + (size_t)b * T_ * S_;

    if (isf) {
        float* ap = alpha + (size_t)b * T_ * S_;
        const int wlo = ch * CL;                 // first owned timestep
        const int te  = wlo + CL - 1;            // last owned timestep
        float u, rcpS, C;
        int ts;
        if (ch == 0) {
            u = initp[lane] * emb[lane];         // t=0 raw emission (no eps), per reference
            if (w == 0) ap[lane] = u;
            float S0 = rlane(wsum_dpp63(u), 63);
            rcpS = __builtin_amdgcn_rcpf(S0);
            C = __log2f(S0);
            ts = 1;
        } else {
            ts = wlo - 32;                       // 32 warm-up steps
            u = emb[(size_t)(ts - 1) * S_ + lane] + 1e-10f;   // proxy start direction
            float S0 = rlane(wsum_dpp63(u), 63);
            rcpS = __builtin_amdgcn_rcpf(S0);
            C = 0.f;
        }
        float ec = emb[(size_t)ts * S_ + lane];
        float e1 = emb[(size_t)(ts + 1) * S_ + lane];
        float e2 = emb[(size_t)(ts + 2) * S_ + lane];
        for (int t = ts; t <= te; t++) {
            float ev = ec + 1e-10f;
            ec = e1; e1 = e2;
            int tn = t + 3 > te ? te : t + 3;
            e2 = emb[(size_t)tn * S_ + lane];    // consumed 3 steps later
            float p0 = 0, p1 = 0, p2 = 0, p3 = 0;
            #pragma unroll
            for (int k = 0; k < 16; k += 4) {
                p0 = fmaf(rlane(u, kbase + k    ), pt[k    ], p0);
                p1 = fmaf(rlane(u, kbase + k + 1), pt[k + 1], p1);
                p2 = fmaf(rlane(u, kbase + k + 2), pt[k + 2], p2);
                p3 = fmaf(rlane(u, kbase + k + 3), pt[k + 3], p3);
            }
            int buf = t & 1;
            part[buf][w][lane] = (p0 + p1) + (p2 + p3);
            __syncthreads();
            float tot = (part[buf][0][lane] + part[buf][1][lane]) +
                        (part[buf][2][lane] + part[buf][3][lane]);
            float un = tot * ev * rcpS;
            u = un;
            if (t >= wlo && w == (t & 3)) ap[(size_t)t * S_ + lane] = un;
            float S = rlane(wsum_dpp63(un), 63); // consumed next step
            rcpS = __builtin_amdgcn_rcpf(S);
            if (w == 0 && t >= wlo) C += __log2f(S);
        }
        if (w == 0 && lane == 0) atomicAdd(&ll[b], C * 0.69314718056f);
    } else {
        float* bp = beta + (size_t)b * T_ * S_;
        const int whi = (ch + 1) * CL - 1;       // last owned timestep
        const int tlo = ch * CL;                 // first owned timestep
        float u, rcpS;
        int ts;
        if (ch == NCH - 1) {
            u = 1.f;                             // beta_{T-1}
            if (w == 0) bp[(size_t)(T_ - 1) * S_ + lane] = 1.f;
            rcpS = 1.f / 64.f;
            ts = T_ - 2;
        } else {
            ts = whi + 31;                       // 31 warm-up steps
            u = 1.f;                             // proxy beta at ts+1
            rcpS = 1.f / 64.f;
        }
        float ec = emb[(size_t)(ts + 1) * S_ + lane];
        float e1 = emb[(size_t)ts * S_ + lane];
        float e2 = emb[(size_t)(ts - 1) * S_ + lane];
        for (int t = ts; t >= tlo; t--) {
            float ev = ec + 1e-10f;              // em_eps[t+1]
            ec = e1; e1 = e2;
            int tp = t - 2 < 0 ? 0 : t - 2;
            e2 = emb[(size_t)tp * S_ + lane];
            float v = u * ev;                    // em*beta
            float p0 = 0, p1 = 0, p2 = 0, p3 = 0;
            #pragma unroll
            for (int k = 0; k < 16; k += 4) {
                p0 = fmaf(rlane(v, kbase + k    ), pt[k    ], p0);
                p1 = fmaf(rlane(v, kbase + k + 1), pt[k + 1], p1);
                p2 = fmaf(rlane(v, kbase + k + 2), pt[k + 2], p2);
                p3 = fmaf(rlane(v, kbase + k + 3), pt[k + 3], p3);
            }
            int buf = t & 1;
            part[buf][w][lane] = (p0 + p1) + (p2 + p3);
            __syncthreads();
            float tot = (part[buf][0][lane] + part[buf][1][lane]) +
                        (part[buf][2][lane] + part[buf][3][lane]);
            float un = tot * rcpS;
            u = un;
            if (t <= whi && w == (t & 3)) bp[(size_t)t * S_ + lane] = un;
            float S = rlane(wsum_dpp63(un), 63);
            rcpS = __builtin_amdgcn_rcpf(S);
        }
    }
}

// ---------------- Kernel D: gamma (in-place over alpha in d_out) + marginals
__global__ __launch_bounds__(256) void gamma_k(const float* __restrict__ beta,
                                               float* __restrict__ out) {
    int wid = threadIdx.x >> 6, lane = threadIdx.x & 63;
    int b = blockIdx.x >> 4;
    int tile = blockIdx.x & 15;
    int t0 = tile * 256 + wid * 64;
    float macc = 0.f;
    size_t base = ((size_t)b * T_ + t0) * 64 + lane;
    for (int i = 0; i < 64; i++) {
        float a  = out[base + (size_t)i * 64];
        float be = beta[((size_t)b * T_ + t0 + i) * 64 + lane];
        float p = a * be;
        float s = rlane(wsum_dpp63(p), 63);
        float g = p * __builtin_amdgcn_rcpf(fmaxf(s, 1e-37f));
        out[base + (size_t)i * 64] = g;
        macc += g;
    }
    atomicAdd(&out[MARG_OFF + b * 64 + lane], macc * (1.0f / T_));
}

extern "C" void kernel_launch(void* const* d_in, const int* in_sizes, int n_in,
                              void* d_out, int out_size, void* d_ws, size_t ws_size,
                              hipStream_t stream) {
    (void)in_sizes; (void)n_in; (void)out_size; (void)ws_size;
    const float* obs    = (const float*)d_in[0];
    const float* W1     = (const float*)d_in[1];
    const float* b1     = (const float*)d_in[2];
    const float* W2     = (const float*)d_in[3];
    const float* b2     = (const float*)d_in[4];
    const float* W3     = (const float*)d_in[5];
    const float* b3     = (const float*)d_in[6];
    const float* LT     = (const float*)d_in[7];
    const float* lip    = (const float*)d_in[8];
    const float* logr   = (const float*)d_in[9];
    const float* logitp = (const float*)d_in[10];
    float* out = (float*)d_out;
    float* ws  = (float*)d_ws;

    hipLaunchKernelGGL(prep_k, dim3(1), dim3(256), 0, stream, LT, lip, logr, logitp, ws, out);
    hipLaunchKernelGGL(mlp_k, dim3(2048), dim3(256), 0, stream,
                       obs, W1, b1, W2, b2, W3, b3, ws + EM_OFF);
    hipLaunchKernelGGL(scan_k, dim3(2 * B_ * NCH), dim3(256), 0, stream,
                       ws + EM_OFF, ws + P_OFF, ws + PT_OFF, ws + INITP_OFF,
                       out + SP_OFF, ws + BETA_OFF, out + LL_OFF);
    hipLaunchKernelGGL(gamma_k, dim3(512), dim3(256), 0, stream, ws + BETA_OFF, out);
}

// Round 6
// 330.280 us; speedup vs baseline: 1.5711x; 1.5711x over previous
//
#include <hip/hip_runtime.h>

#define B_ 32
#define T_ 4096
#define D_ 64
#define H_ 128
#define S_ 64
#define BTS (B_*T_*S_)   /* 8388608 */

#define NCH 32      /* chunks per sequence */
#define CL  128     /* chunk length */

// workspace float offsets
#define EM_OFF    0
#define BETA_OFF  BTS
#define P_OFF     (2*BTS)
#define PT_OFF    (2*BTS + 4096)
#define INITP_OFF (2*BTS + 8192)
// split-bf16 weights parked in the TAIL of the beta region (32768 floats =
// 65536 ushorts). Written by prep_k, read by mlp_k, overwritten by scan_k
// (which runs after mlp_k) — zero extra workspace footprint.
#define WSPLIT_OFF (BETA_OFF + BTS - 32768)
// ushort offsets inside the weight region:
//   W1T hi [128][64] @0      lo @8192
//   W2T hi [128][128]@16384  lo @32768
//   W3T hi [64][128] @49152  lo @57344
// output float offsets
#define SP_OFF   0
#define MARG_OFF BTS
#define DUR_OFF  (BTS + 2048)
#define LL_OFF   (BTS + 2112)

typedef __attribute__((ext_vector_type(8))) short short8;
typedef __attribute__((ext_vector_type(4))) float f32x4;
#define MFMA_BF16 __builtin_amdgcn_mfma_f32_16x16x32_bf16

__device__ __forceinline__ float wsum(float v) {
    #pragma unroll
    for (int m = 1; m < 64; m <<= 1) v += __shfl_xor(v, m, 64);
    return v;
}
__device__ __forceinline__ float wmax(float v) {
    #pragma unroll
    for (int m = 1; m < 64; m <<= 1) v = fmaxf(v, __shfl_xor(v, m, 64));
    return v;
}
__device__ __forceinline__ float rlane(float v, int k) {
    return __int_as_float(__builtin_amdgcn_readlane(__float_as_int(v), k));
}
template<int CTRL, int RM>
__device__ __forceinline__ float dppadd(float v) {
    return v + __int_as_float(__builtin_amdgcn_update_dpp(
        0, __float_as_int(v), CTRL, RM, 0xf, false));
}
__device__ __forceinline__ float wsum_dpp63(float v) {
    v = dppadd<0x111, 0xf>(v);
    v = dppadd<0x112, 0xf>(v);
    v = dppadd<0x114, 0xf>(v);
    v = dppadd<0x118, 0xf>(v);
    v = dppadd<0x142, 0xa>(v);
    v = dppadd<0x143, 0xc>(v);   // lane63 = total
    return v;
}
__device__ __forceinline__ unsigned short bfhi(float x) {
    return (unsigned short)(__float_as_uint(x) >> 16);   // truncate to bf16
}
__device__ __forceinline__ float bf2f(unsigned short h) {
    return __uint_as_float(((unsigned int)h) << 16);
}
__device__ __forceinline__ void split8(const float* x8, short8& hi, short8& lo) {
    #pragma unroll
    for (int i = 0; i < 8; i++) {
        unsigned short h = bfhi(x8[i]);
        hi[i] = (short)h;
        lo[i] = (short)bfhi(x8[i] - bf2f(h));
    }
}

// ---------------- Kernel A: prep (trans probs, init, durations, weight split, zeroing)
__global__ __launch_bounds__(256) void prep_k(const float* __restrict__ LT,
                                              const float* __restrict__ lip,
                                              const float* __restrict__ logr,
                                              const float* __restrict__ logitp,
                                              const float* __restrict__ W1,
                                              const float* __restrict__ W2,
                                              const float* __restrict__ W3,
                                              float* __restrict__ ws,
                                              float* __restrict__ out) {
    int tid = threadIdx.x, wid = tid >> 6, lane = tid & 63;
    for (int r = wid; r < S_; r += 4) {
        float x = (lane == r) ? -1e10f : LT[r * S_ + lane];
        float m = wmax(x);
        float e = __expf(x - m);
        float s = wsum(e);
        float p = e / s + 1e-10f;
        ws[P_OFF  + r * S_ + lane] = p;
        ws[PT_OFF + lane * S_ + r] = p;
    }
    if (wid == 0) {
        float x = lip[lane];
        float m = wmax(x);
        float e = __expf(x - m);
        float s = wsum(e);
        ws[INITP_OFF + lane] = e / s;
    } else if (wid == 1) {
        float r = __expf(logr[lane]);
        float p = 1.f / (1.f + __expf(-logitp[lane]));
        out[DUR_OFF + lane] = r * (1.f - p) / p;
    }
    for (int i = tid; i < B_ * S_; i += 256) out[MARG_OFF + i] = 0.f;
    if (tid < B_) out[LL_OFF + tid] = 0.f;

    // split-bf16 transposed weights
    unsigned short* wsp = (unsigned short*)(ws + WSPLIT_OFF);
    for (int i = tid; i < 8192; i += 256) {        // W1T[j][d] = W1[d][j]
        int j = i >> 6, d = i & 63;
        float x = W1[d * 128 + j];
        unsigned short h = bfhi(x);
        wsp[i] = h;
        wsp[8192 + i] = bfhi(x - bf2f(h));
        // i == j*64 + d
    }
    for (int i = tid; i < 16384; i += 256) {       // W2T[j][k] = W2[k][j]
        int j = i >> 7, k = i & 127;
        float x = W2[k * 128 + j];
        unsigned short h = bfhi(x);
        wsp[16384 + i] = h;
        wsp[32768 + i] = bfhi(x - bf2f(h));
    }
    for (int i = tid; i < 8192; i += 256) {        // W3T[s][k] = W3[k][s]
        int s = i >> 7, k = i & 127;
        float x = W3[k * 64 + s];
        unsigned short h = bfhi(x);
        wsp[49152 + i] = h;
        wsp[57344 + i] = bfhi(x - bf2f(h));
    }
}

// ---------------- Kernel B: emission MLP via split-bf16 MFMA + softmax -> em
// Per wave: 32 rows (2 m-tiles). D-layout -> A-layout transposes through a
// per-wave 16x132 fp32 LDS buffer (pad 132: <=2-way conflicts = free; rows
// 528B = 16B-aligned for ds_read_b128).
__global__ __launch_bounds__(256) void mlp_k(const float* __restrict__ obs,
                                             const unsigned short* __restrict__ wsp,
                                             const float* __restrict__ b1,
                                             const float* __restrict__ b2,
                                             const float* __restrict__ b3,
                                             float* __restrict__ em) {
    __shared__ float lds[4 * 2112];
    int tid = threadIdx.x, wid = tid >> 6, lane = tid & 63;
    int c = lane & 15, q = lane >> 4;
    float* lb = lds + wid * 2112;
    int r0 = blockIdx.x * 128 + wid * 32;

    // ---- X A-frags (fp32 -> split bf16), A[m=c][k=q*8+j] ----
    short8 a1h[2][2], a1l[2][2];
    #pragma unroll
    for (int mt = 0; mt < 2; mt++) {
        #pragma unroll
        for (int kq = 0; kq < 2; kq++) {
            const float* xp = obs + (size_t)(r0 + mt * 16 + c) * 64 + kq * 32 + q * 8;
            float x8[8];
            *(float4*)x8       = *(const float4*)xp;
            *(float4*)(x8 + 4) = *(const float4*)(xp + 4);
            split8(x8, a1h[mt][kq], a1l[mt][kq]);
        }
    }

    // ---- layer 1: D1 = X @ W1  (out 128 = 8 n-tiles, K=64 = 2 k-frags) ----
    f32x4 D[2][8];
    #pragma unroll
    for (int nt = 0; nt < 8; nt++) {
        const unsigned short* wp = wsp + (nt * 16 + c) * 64 + q * 8;
        short8 bh0 = *(const short8*)(wp);
        short8 bh1 = *(const short8*)(wp + 32);
        short8 bl0 = *(const short8*)(wp + 8192);
        short8 bl1 = *(const short8*)(wp + 8192 + 32);
        #pragma unroll
        for (int mt = 0; mt < 2; mt++) {
            f32x4 acc = {0.f, 0.f, 0.f, 0.f};
            acc = MFMA_BF16(a1h[mt][0], bh0, acc, 0, 0, 0);
            acc = MFMA_BF16(a1h[mt][0], bl0, acc, 0, 0, 0);
            acc = MFMA_BF16(a1l[mt][0], bh0, acc, 0, 0, 0);
            acc = MFMA_BF16(a1h[mt][1], bh1, acc, 0, 0, 0);
            acc = MFMA_BF16(a1h[mt][1], bl1, acc, 0, 0, 0);
            acc = MFMA_BF16(a1l[mt][1], bh1, acc, 0, 0, 0);
            D[mt][nt] = acc;
        }
    }

    // ---- bias+relu, transpose per m-tile, re-split -> layer-2 A-frags ----
    short8 a2h[2][4], a2l[2][4];
    #pragma unroll
    for (int mt = 0; mt < 2; mt++) {
        #pragma unroll
        for (int nt = 0; nt < 8; nt++) {
            float bb = b1[nt * 16 + c];
            f32x4 a = D[mt][nt];
            #pragma unroll
            for (int r = 0; r < 4; r++)
                lb[(q * 4 + r) * 132 + nt * 16 + c] = fmaxf(a[r] + bb, 0.f);
        }
        #pragma unroll
        for (int kq = 0; kq < 4; kq++) {
            float h8[8];
            *(float4*)h8       = *(const float4*)&lb[c * 132 + kq * 32 + q * 8];
            *(float4*)(h8 + 4) = *(const float4*)&lb[c * 132 + kq * 32 + q * 8 + 4];
            split8(h8, a2h[mt][kq], a2l[mt][kq]);
        }
        __asm__ __volatile__("s_waitcnt lgkmcnt(0)" ::: "memory");
    }

    // ---- layer 2: D2 = H1 @ W2 (out 128, K=128 = 4 k-frags) ----
    #pragma unroll
    for (int nt = 0; nt < 8; nt++) {
        const unsigned short* wp = wsp + 16384 + (nt * 16 + c) * 128 + q * 8;
        short8 bh[4], bl[4];
        #pragma unroll
        for (int kq = 0; kq < 4; kq++) {
            bh[kq] = *(const short8*)(wp + kq * 32);
            bl[kq] = *(const short8*)(wp + 16384 + kq * 32);
        }
        #pragma unroll
        for (int mt = 0; mt < 2; mt++) {
            f32x4 acc = {0.f, 0.f, 0.f, 0.f};
            #pragma unroll
            for (int kq = 0; kq < 4; kq++) {
                acc = MFMA_BF16(a2h[mt][kq], bh[kq], acc, 0, 0, 0);
                acc = MFMA_BF16(a2h[mt][kq], bl[kq], acc, 0, 0, 0);
                acc = MFMA_BF16(a2l[mt][kq], bh[kq], acc, 0, 0, 0);
            }
            D[mt][nt] = acc;
        }
    }

    // ---- bias+relu, transpose, re-split -> layer-3 A-frags ----
    short8 a3h[2][4], a3l[2][4];
    #pragma unroll
    for (int mt = 0; mt < 2; mt++) {
        #pragma unroll
        for (int nt = 0; nt < 8; nt++) {
            float bb = b2[nt * 16 + c];
            f32x4 a = D[mt][nt];
            #pragma unroll
            for (int r = 0; r < 4; r++)
                lb[(q * 4 + r) * 132 + nt * 16 + c] = fmaxf(a[r] + bb, 0.f);
        }
        #pragma unroll
        for (int kq = 0; kq < 4; kq++) {
            float h8[8];
            *(float4*)h8       = *(const float4*)&lb[c * 132 + kq * 32 + q * 8];
            *(float4*)(h8 + 4) = *(const float4*)&lb[c * 132 + kq * 32 + q * 8 + 4];
            split8(h8, a3h[mt][kq], a3l[mt][kq]);
        }
        __asm__ __volatile__("s_waitcnt lgkmcnt(0)" ::: "memory");
    }

    // ---- layer 3: logits = H2 @ W3 (out 64 = 4 n-tiles, K=128) ----
    f32x4 L[2][4];
    #pragma unroll
    for (int nt = 0; nt < 4; nt++) {
        const unsigned short* wp = wsp + 49152 + (nt * 16 + c) * 128 + q * 8;
        short8 bh[4], bl[4];
        #pragma unroll
        for (int kq = 0; kq < 4; kq++) {
            bh[kq] = *(const short8*)(wp + kq * 32);
            bl[kq] = *(const short8*)(wp + 8192 + kq * 32);
        }
        #pragma unroll
        for (int mt = 0; mt < 2; mt++) {
            f32x4 acc = {0.f, 0.f, 0.f, 0.f};
            #pragma unroll
            for (int kq = 0; kq < 4; kq++) {
                acc = MFMA_BF16(a3h[mt][kq], bh[kq], acc, 0, 0, 0);
                acc = MFMA_BF16(a3h[mt][kq], bl[kq], acc, 0, 0, 0);
                acc = MFMA_BF16(a3l[mt][kq], bh[kq], acc, 0, 0, 0);
            }
            L[mt][nt] = acc;
        }
    }

    // ---- bias + softmax per row (row = r0 + mt*16 + q*4 + r; col = nt*16 + c)
    float bb3[4];
    #pragma unroll
    for (int nt = 0; nt < 4; nt++) bb3[nt] = b3[nt * 16 + c];
    #pragma unroll
    for (int mt = 0; mt < 2; mt++) {
        #pragma unroll
        for (int r = 0; r < 4; r++) {
            float v[4];
            #pragma unroll
            for (int nt = 0; nt < 4; nt++) v[nt] = L[mt][nt][r] + bb3[nt];
            float m = fmaxf(fmaxf(v[0], v[1]), fmaxf(v[2], v[3]));
            #pragma unroll
            for (int msk = 1; msk < 16; msk <<= 1) m = fmaxf(m, __shfl_xor(m, msk, 64));
            float e[4], s = 0.f;
            #pragma unroll
            for (int nt = 0; nt < 4; nt++) { e[nt] = __expf(v[nt] - m); s += e[nt]; }
            #pragma unroll
            for (int msk = 1; msk < 16; msk <<= 1) s += __shfl_xor(s, msk, 64);
            float rs = __builtin_amdgcn_rcpf(s);
            size_t row = (size_t)(r0 + mt * 16 + q * 4 + r);
            #pragma unroll
            for (int nt = 0; nt < 4; nt++)
                em[row * 64 + nt * 16 + c] = e[nt] * rs;
        }
    }
}

// ---------------- Kernel C: chunked fwd/bwd recursions, ONE wave per chain.
// Full 64-wide matvec via readlane broadcast (issue-bound, no LDS/barriers).
__global__ __launch_bounds__(64) void scan_k(const float* __restrict__ em,
                                             const float* __restrict__ Pm,
                                             const float* __restrict__ PTm,
                                             const float* __restrict__ initp,
                                             float* __restrict__ alpha,   // d_out SP region
                                             float* __restrict__ beta,    // ws
                                             float* __restrict__ ll) {
    int blk = blockIdx.x, lane = threadIdx.x;
    bool isf = blk < B_ * NCH;
    int lin  = isf ? blk : blk - B_ * NCH;
    int b  = lin / NCH;
    int ch = lin % NCH;
    const float* M = isf ? PTm : Pm;
    float pt[64];
    #pragma unroll
    for (int i = 0; i < 16; i++) {
        float4 v = ((const float4*)(M + lane * 64))[i];
        pt[4*i] = v.x; pt[4*i+1] = v.y; pt[4*i+2] = v.z; pt[4*i+3] = v.w;
    }
    const float* emb = em + (size_t)b * T_ * S_;

    if (isf) {
        float* ap = alpha + (size_t)b * T_ * S_;
        const int wlo = ch * CL;
        const int te  = wlo + CL - 1;
        float u, rcpS, C;
        int ts;
        if (ch == 0) {
            u = initp[lane] * emb[lane];         // t=0 raw emission (no eps), per reference
            ap[lane] = u;
            float S0 = rlane(wsum_dpp63(u), 63);
            rcpS = __builtin_amdgcn_rcpf(S0);
            C = __log2f(S0);
            ts = 1;
        } else {
            ts = wlo - 32;                       // 32 warm-up steps
            u = emb[(size_t)(ts - 1) * S_ + lane] + 1e-10f;   // proxy start direction
            float S0 = rlane(wsum_dpp63(u), 63);
            rcpS = __builtin_amdgcn_rcpf(S0);
            C = 0.f;
        }
        float ec = emb[(size_t)ts * S_ + lane];
        float e1 = emb[(size_t)(ts + 1) * S_ + lane];
        float e2 = emb[(size_t)(ts + 2) * S_ + lane];
        for (int t = ts; t <= te; t++) {
            float ev = ec + 1e-10f;
            ec = e1; e1 = e2;
            int tn = t + 3 > te ? te : t + 3;
            e2 = emb[(size_t)tn * S_ + lane];
            float a0 = 0, a1 = 0, a2 = 0, a3 = 0;
            #pragma unroll
            for (int k = 0; k < 64; k += 4) {
                a0 = fmaf(rlane(u, k    ), pt[k    ], a0);
                a1 = fmaf(rlane(u, k + 1), pt[k + 1], a1);
                a2 = fmaf(rlane(u, k + 2), pt[k + 2], a2);
                a3 = fmaf(rlane(u, k + 3), pt[k + 3], a3);
            }
            float un = ((a0 + a1) + (a2 + a3)) * ev * rcpS;
            u = un;
            if (t >= wlo) ap[(size_t)t * S_ + lane] = un;
            float S = rlane(wsum_dpp63(un), 63);
            rcpS = __builtin_amdgcn_rcpf(S);
            if (t >= wlo) C += __log2f(S);
        }
        if (lane == 0) atomicAdd(&ll[b], C * 0.69314718056f);
    } else {
        float* bp = beta + (size_t)b * T_ * S_;
        const int whi = (ch + 1) * CL - 1;
        const int tlo = ch * CL;
        float u, rcpS;
        int ts;
        if (ch == NCH - 1) {
            u = 1.f;
            bp[(size_t)(T_ - 1) * S_ + lane] = 1.f;
            rcpS = 1.f / 64.f;
            ts = T_ - 2;
        } else {
            ts = whi + 31;                       // 31 warm-up steps
            u = 1.f;
            rcpS = 1.f / 64.f;
        }
        float ec = emb[(size_t)(ts + 1) * S_ + lane];
        float e1 = emb[(size_t)ts * S_ + lane];
        float e2 = emb[(size_t)(ts - 1) * S_ + lane];
        for (int t = ts; t >= tlo; t--) {
            float ev = ec + 1e-10f;              // em_eps[t+1]
            ec = e1; e1 = e2;
            int tp = t - 2 < 0 ? 0 : t - 2;
            e2 = emb[(size_t)tp * S_ + lane];
            float v = u * ev;
            float a0 = 0, a1 = 0, a2 = 0, a3 = 0;
            #pragma unroll
            for (int k = 0; k < 64; k += 4) {
                a0 = fmaf(rlane(v, k    ), pt[k    ], a0);
                a1 = fmaf(rlane(v, k + 1), pt[k + 1], a1);
                a2 = fmaf(rlane(v, k + 2), pt[k + 2], a2);
                a3 = fmaf(rlane(v, k + 3), pt[k + 3], a3);
            }
            float un = ((a0 + a1) + (a2 + a3)) * rcpS;
            u = un;
            if (t <= whi) bp[(size_t)t * S_ + lane] = un;
            float S = rlane(wsum_dpp63(un), 63);
            rcpS = __builtin_amdgcn_rcpf(S);
        }
    }
}

// ---------------- Kernel D: gamma (in-place over alpha in d_out) + marginals
__global__ __launch_bounds__(256) void gamma_k(const float* __restrict__ beta,
                                               float* __restrict__ out) {
    int wid = threadIdx.x >> 6, lane = threadIdx.x & 63;
    int b = blockIdx.x >> 4;
    int tile = blockIdx.x & 15;
    int t0 = tile * 256 + wid * 64;
    float macc = 0.f;
    size_t base = ((size_t)b * T_ + t0) * 64 + lane;
    for (int i = 0; i < 64; i++) {
        float a  = out[base + (size_t)i * 64];
        float be = beta[((size_t)b * T_ + t0 + i) * 64 + lane];
        float p = a * be;
        float s = rlane(wsum_dpp63(p), 63);
        float g = p * __builtin_amdgcn_rcpf(fmaxf(s, 1e-37f));
        out[base + (size_t)i * 64] = g;
        macc += g;
    }
    atomicAdd(&out[MARG_OFF + b * 64 + lane], macc * (1.0f / T_));
}

extern "C" void kernel_launch(void* const* d_in, const int* in_sizes, int n_in,
                              void* d_out, int out_size, void* d_ws, size_t ws_size,
                              hipStream_t stream) {
    (void)in_sizes; (void)n_in; (void)out_size; (void)ws_size;
    const float* obs    = (const float*)d_in[0];
    const float* W1     = (const float*)d_in[1];
    const float* b1     = (const float*)d_in[2];
    const float* W2     = (const float*)d_in[3];
    const float* b2     = (const float*)d_in[4];
    const float* W3     = (const float*)d_in[5];
    const float* b3     = (const float*)d_in[6];
    const float* LT     = (const float*)d_in[7];
    const float* lip    = (const float*)d_in[8];
    const float* logr   = (const float*)d_in[9];
    const float* logitp = (const float*)d_in[10];
    float* out = (float*)d_out;
    float* ws  = (float*)d_ws;

    hipLaunchKernelGGL(prep_k, dim3(1), dim3(256), 0, stream,
                       LT, lip, logr, logitp, W1, W2, W3, ws, out);
    hipLaunchKernelGGL(mlp_k, dim3(1024), dim3(256), 0, stream,
                       obs, (const unsigned short*)(ws + WSPLIT_OFF),
                       b1, b2, b3, ws + EM_OFF);
    hipLaunchKernelGGL(scan_k, dim3(2 * B_ * NCH), dim3(64), 0, stream,
                       ws + EM_OFF, ws + P_OFF, ws + PT_OFF, ws + INITP_OFF,
                       out + SP_OFF, ws + BETA_OFF, out + LL_OFF);
    hipLaunchKernelGGL(gamma_k, dim3(512), dim3(256), 0, stream, ws + BETA_OFF, out);
}

// Round 7
// 266.888 us; speedup vs baseline: 1.9442x; 1.2375x over previous
//
#include <hip/hip_runtime.h>

#define B_ 32
#define T_ 4096
#define D_ 64
#define H_ 128
#define S_ 64
#define BTS (B_*T_*S_)   /* 8388608 */

#define NCH 128     /* chunks per sequence */
#define CL  32      /* chunk length */

// workspace float offsets
#define EM_OFF    0
#define BETA_OFF  BTS
#define P_OFF     (2*BTS)
#define PT_OFF    (2*BTS + 4096)
#define INITP_OFF (2*BTS + 8192)
// split-bf16 weights parked in the TAIL of the beta region (32768 floats =
// 65536 ushorts). Written by prep_k, read by mlp_k, overwritten by scan_k.
#define WSPLIT_OFF (BETA_OFF + BTS - 32768)
// output float offsets
#define SP_OFF   0
#define MARG_OFF BTS
#define DUR_OFF  (BTS + 2048)
#define LL_OFF   (BTS + 2112)

typedef __attribute__((ext_vector_type(8))) short short8;
typedef __attribute__((ext_vector_type(4))) float f32x4;
#define MFMA_BF16 __builtin_amdgcn_mfma_f32_16x16x32_bf16

__device__ __forceinline__ float wsum(float v) {
    #pragma unroll
    for (int m = 1; m < 64; m <<= 1) v += __shfl_xor(v, m, 64);
    return v;
}
__device__ __forceinline__ float wmax(float v) {
    #pragma unroll
    for (int m = 1; m < 64; m <<= 1) v = fmaxf(v, __shfl_xor(v, m, 64));
    return v;
}
__device__ __forceinline__ float rlane(float v, int k) {
    return __int_as_float(__builtin_amdgcn_readlane(__float_as_int(v), k));
}
template<int CTRL, int RM>
__device__ __forceinline__ float dppadd(float v) {
    return v + __int_as_float(__builtin_amdgcn_update_dpp(
        0, __float_as_int(v), CTRL, RM, 0xf, false));
}
__device__ __forceinline__ float wsum_dpp63(float v) {
    v = dppadd<0x111, 0xf>(v);
    v = dppadd<0x112, 0xf>(v);
    v = dppadd<0x114, 0xf>(v);
    v = dppadd<0x118, 0xf>(v);
    v = dppadd<0x142, 0xa>(v);
    v = dppadd<0x143, 0xc>(v);   // lane63 = total
    return v;
}
__device__ __forceinline__ unsigned short bfhi(float x) {
    return (unsigned short)(__float_as_uint(x) >> 16);   // truncate to bf16
}
__device__ __forceinline__ float bf2f(unsigned short h) {
    return __uint_as_float(((unsigned int)h) << 16);
}
__device__ __forceinline__ void split8(const float* x8, short8& hi, short8& lo) {
    #pragma unroll
    for (int i = 0; i < 8; i++) {
        unsigned short h = bfhi(x8[i]);
        hi[i] = (short)h;
        lo[i] = (short)bfhi(x8[i] - bf2f(h));
    }
}

// ---------------- Kernel A: prep (trans probs, init, durations, weight split, zeroing)
__global__ __launch_bounds__(256) void prep_k(const float* __restrict__ LT,
                                              const float* __restrict__ lip,
                                              const float* __restrict__ logr,
                                              const float* __restrict__ logitp,
                                              const float* __restrict__ W1,
                                              const float* __restrict__ W2,
                                              const float* __restrict__ W3,
                                              float* __restrict__ ws,
                                              float* __restrict__ out) {
    int tid = threadIdx.x, wid = tid >> 6, lane = tid & 63;
    if (blockIdx.x == 0) {
        for (int r = wid; r < S_; r += 4) {
            float x = (lane == r) ? -1e10f : LT[r * S_ + lane];
            float m = wmax(x);
            float e = __expf(x - m);
            float s = wsum(e);
            float p = e / s + 1e-10f;
            ws[P_OFF  + r * S_ + lane] = p;
            ws[PT_OFF + lane * S_ + r] = p;
        }
        if (wid == 0) {
            float x = lip[lane];
            float m = wmax(x);
            float e = __expf(x - m);
            float s = wsum(e);
            ws[INITP_OFF + lane] = e / s;
        } else if (wid == 1) {
            float r = __expf(logr[lane]);
            float p = 1.f / (1.f + __expf(-logitp[lane]));
            out[DUR_OFF + lane] = r * (1.f - p) / p;
        }
        for (int i = tid; i < B_ * S_; i += 256) out[MARG_OFF + i] = 0.f;
        if (tid < B_) out[LL_OFF + tid] = 0.f;
    }
    // split-bf16 transposed weights (all 8 blocks stride)
    int gid = blockIdx.x * 256 + tid, gstr = 8 * 256;
    unsigned short* wsp = (unsigned short*)(ws + WSPLIT_OFF);
    for (int i = gid; i < 8192; i += gstr) {       // W1T[j][d] = W1[d][j]
        int j = i >> 6, d = i & 63;
        float x = W1[d * 128 + j];
        unsigned short h = bfhi(x);
        wsp[i] = h;
        wsp[8192 + i] = bfhi(x - bf2f(h));
    }
    for (int i = gid; i < 16384; i += gstr) {      // W2T[j][k] = W2[k][j]
        int j = i >> 7, k = i & 127;
        float x = W2[k * 128 + j];
        unsigned short h = bfhi(x);
        wsp[16384 + i] = h;
        wsp[32768 + i] = bfhi(x - bf2f(h));
    }
    for (int i = gid; i < 8192; i += gstr) {       // W3T[s][k] = W3[k][s]
        int s = i >> 7, k = i & 127;
        float x = W3[k * 64 + s];
        unsigned short h = bfhi(x);
        wsp[49152 + i] = h;
        wsp[57344 + i] = bfhi(x - bf2f(h));
    }
}

// ---------------- Kernel B: emission MLP via split-bf16 MFMA + softmax -> em
__global__ __launch_bounds__(256) void mlp_k(const float* __restrict__ obs,
                                             const unsigned short* __restrict__ wsp,
                                             const float* __restrict__ b1,
                                             const float* __restrict__ b2,
                                             const float* __restrict__ b3,
                                             float* __restrict__ em) {
    __shared__ float lds[4 * 2112];
    int tid = threadIdx.x, wid = tid >> 6, lane = tid & 63;
    int c = lane & 15, q = lane >> 4;
    float* lb = lds + wid * 2112;
    int r0 = blockIdx.x * 128 + wid * 32;

    short8 a1h[2][2], a1l[2][2];
    #pragma unroll
    for (int mt = 0; mt < 2; mt++) {
        #pragma unroll
        for (int kq = 0; kq < 2; kq++) {
            const float* xp = obs + (size_t)(r0 + mt * 16 + c) * 64 + kq * 32 + q * 8;
            float x8[8];
            *(float4*)x8       = *(const float4*)xp;
            *(float4*)(x8 + 4) = *(const float4*)(xp + 4);
            split8(x8, a1h[mt][kq], a1l[mt][kq]);
        }
    }

    f32x4 D[2][8];
    #pragma unroll
    for (int nt = 0; nt < 8; nt++) {
        const unsigned short* wp = wsp + (nt * 16 + c) * 64 + q * 8;
        short8 bh0 = *(const short8*)(wp);
        short8 bh1 = *(const short8*)(wp + 32);
        short8 bl0 = *(const short8*)(wp + 8192);
        short8 bl1 = *(const short8*)(wp + 8192 + 32);
        #pragma unroll
        for (int mt = 0; mt < 2; mt++) {
            f32x4 acc = {0.f, 0.f, 0.f, 0.f};
            acc = MFMA_BF16(a1h[mt][0], bh0, acc, 0, 0, 0);
            acc = MFMA_BF16(a1h[mt][0], bl0, acc, 0, 0, 0);
            acc = MFMA_BF16(a1l[mt][0], bh0, acc, 0, 0, 0);
            acc = MFMA_BF16(a1h[mt][1], bh1, acc, 0, 0, 0);
            acc = MFMA_BF16(a1h[mt][1], bl1, acc, 0, 0, 0);
            acc = MFMA_BF16(a1l[mt][1], bh1, acc, 0, 0, 0);
            D[mt][nt] = acc;
        }
    }

    short8 a2h[2][4], a2l[2][4];
    #pragma unroll
    for (int mt = 0; mt < 2; mt++) {
        #pragma unroll
        for (int nt = 0; nt < 8; nt++) {
            float bb = b1[nt * 16 + c];
            f32x4 a = D[mt][nt];
            #pragma unroll
            for (int r = 0; r < 4; r++)
                lb[(q * 4 + r) * 132 + nt * 16 + c] = fmaxf(a[r] + bb, 0.f);
        }
        #pragma unroll
        for (int kq = 0; kq < 4; kq++) {
            float h8[8];
            *(float4*)h8       = *(const float4*)&lb[c * 132 + kq * 32 + q * 8];
            *(float4*)(h8 + 4) = *(const float4*)&lb[c * 132 + kq * 32 + q * 8 + 4];
            split8(h8, a2h[mt][kq], a2l[mt][kq]);
        }
        __asm__ __volatile__("s_waitcnt lgkmcnt(0)" ::: "memory");
    }

    #pragma unroll
    for (int nt = 0; nt < 8; nt++) {
        const unsigned short* wp = wsp + 16384 + (nt * 16 + c) * 128 + q * 8;
        short8 bh[4], bl[4];
        #pragma unroll
        for (int kq = 0; kq < 4; kq++) {
            bh[kq] = *(const short8*)(wp + kq * 32);
            bl[kq] = *(const short8*)(wp + 16384 + kq * 32);
        }
        #pragma unroll
        for (int mt = 0; mt < 2; mt++) {
            f32x4 acc = {0.f, 0.f, 0.f, 0.f};
            #pragma unroll
            for (int kq = 0; kq < 4; kq++) {
                acc = MFMA_BF16(a2h[mt][kq], bh[kq], acc, 0, 0, 0);
                acc = MFMA_BF16(a2h[mt][kq], bl[kq], acc, 0, 0, 0);
                acc = MFMA_BF16(a2l[mt][kq], bh[kq], acc, 0, 0, 0);
            }
            D[mt][nt] = acc;
        }
    }

    short8 a3h[2][4], a3l[2][4];
    #pragma unroll
    for (int mt = 0; mt < 2; mt++) {
        #pragma unroll
        for (int nt = 0; nt < 8; nt++) {
            float bb = b2[nt * 16 + c];
            f32x4 a = D[mt][nt];
            #pragma unroll
            for (int r = 0; r < 4; r++)
                lb[(q * 4 + r) * 132 + nt * 16 + c] = fmaxf(a[r] + bb, 0.f);
        }
        #pragma unroll
        for (int kq = 0; kq < 4; kq++) {
            float h8[8];
            *(float4*)h8       = *(const float4*)&lb[c * 132 + kq * 32 + q * 8];
            *(float4*)(h8 + 4) = *(const float4*)&lb[c * 132 + kq * 32 + q * 8 + 4];
            split8(h8, a3h[mt][kq], a3l[mt][kq]);
        }
        __asm__ __volatile__("s_waitcnt lgkmcnt(0)" ::: "memory");
    }

    f32x4 L[2][4];
    #pragma unroll
    for (int nt = 0; nt < 4; nt++) {
        const unsigned short* wp = wsp + 49152 + (nt * 16 + c) * 128 + q * 8;
        short8 bh[4], bl[4];
        #pragma unroll
        for (int kq = 0; kq < 4; kq++) {
            bh[kq] = *(const short8*)(wp + kq * 32);
            bl[kq] = *(const short8*)(wp + 8192 + kq * 32);
        }
        #pragma unroll
        for (int mt = 0; mt < 2; mt++) {
            f32x4 acc = {0.f, 0.f, 0.f, 0.f};
            #pragma unroll
            for (int kq = 0; kq < 4; kq++) {
                acc = MFMA_BF16(a3h[mt][kq], bh[kq], acc, 0, 0, 0);
                acc = MFMA_BF16(a3h[mt][kq], bl[kq], acc, 0, 0, 0);
                acc = MFMA_BF16(a3l[mt][kq], bh[kq], acc, 0, 0, 0);
            }
            L[mt][nt] = acc;
        }
    }

    float bb3[4];
    #pragma unroll
    for (int nt = 0; nt < 4; nt++) bb3[nt] = b3[nt * 16 + c];
    #pragma unroll
    for (int mt = 0; mt < 2; mt++) {
        #pragma unroll
        for (int r = 0; r < 4; r++) {
            float v[4];
            #pragma unroll
            for (int nt = 0; nt < 4; nt++) v[nt] = L[mt][nt][r] + bb3[nt];
            float m = fmaxf(fmaxf(v[0], v[1]), fmaxf(v[2], v[3]));
            #pragma unroll
            for (int msk = 1; msk < 16; msk <<= 1) m = fmaxf(m, __shfl_xor(m, msk, 64));
            float e[4], s = 0.f;
            #pragma unroll
            for (int nt = 0; nt < 4; nt++) { e[nt] = __expf(v[nt] - m); s += e[nt]; }
            #pragma unroll
            for (int msk = 1; msk < 16; msk <<= 1) s += __shfl_xor(s, msk, 64);
            float rs = __builtin_amdgcn_rcpf(s);
            size_t row = (size_t)(r0 + mt * 16 + q * 4 + r);
            #pragma unroll
            for (int nt = 0; nt < 4; nt++)
                em[row * 64 + nt * 16 + c] = e[nt] * rs;
        }
    }
}

// ---------------- Kernel C: MFMA-batched chunked fwd/bwd recursions.
// One wave = 16 chains (16 b's, same chunk). State in MFMA A-layout
// (chain=lane&15, states k=(lane>>4)*8+j, 2 k-frags). Matvec D = U x B with
// B = P/P^T split-bf16 resident in VGPRs (24 MFMA/step, same layout
// conventions validated in mlp_k). C->A transpose via 16x68 LDS (pad 68:
// 2-way conflicts free, rows 272B keep b128 alignment). Per-chain sums via
// shfl_xor 16/32 (lanes with equal lane&15 hold the same chain).
__global__ __launch_bounds__(64) void scan_k(const float* __restrict__ em,
                                             const float* __restrict__ Pm,
                                             const float* __restrict__ PTm,
                                             const float* __restrict__ initp,
                                             float* __restrict__ alpha,   // d_out SP region
                                             float* __restrict__ beta,    // ws
                                             float* __restrict__ ll) {
    __shared__ float lds[16 * 68];
    const int lane = threadIdx.x, c = lane & 15, q = lane >> 4;
    int blk = blockIdx.x;
    const bool isf = blk < 2 * NCH;
    int lin = isf ? blk : blk - 2 * NCH;
    int bg = lin / NCH, ch = lin % NCH;
    const int b = bg * 16 + c;
    const float* M = isf ? PTm : Pm;          // B[k][n] = M[n*64 + k]

    // resident B-frags: B[k = kf*32 + q*8 + j][n = nt*16 + c]
    short8 Bh[4][2], Bl[4][2];
    #pragma unroll
    for (int nt = 0; nt < 4; nt++) {
        #pragma unroll
        for (int kf = 0; kf < 2; kf++) {
            const float* mp = M + (nt * 16 + c) * 64 + kf * 32 + q * 8;
            float m8[8];
            *(float4*)m8       = *(const float4*)mp;
            *(float4*)(m8 + 4) = *(const float4*)(mp + 4);
            split8(m8, Bh[nt][kf], Bl[nt][kf]);
        }
    }

    const size_t ebase = (size_t)b * T_ * 64 + q * 8;
    float* outp = isf ? alpha : beta;
    const int wrofs = (q * 4) * 68 + c;       // + r*68 + nt*16
    const int rdofs = c * 68 + q * 8;         // + j (+32 for frag 1)

    float w[16];      // state vector (fwd: alpha-hat; bwd: w = beta*e carried)
    float rcpS, C = 0.f;

    auto loadE = [&](int t, float* e) {
        const float* p = em + ebase + (size_t)t * 64;
        *(float4*)(e)      = *(const float4*)(p);
        *(float4*)(e + 4)  = *(const float4*)(p + 4);
        *(float4*)(e + 8)  = *(const float4*)(p + 32);
        *(float4*)(e + 12) = *(const float4*)(p + 36);
    };
    auto storeY = [&](const float* y, int t) {
        float* p = outp + ebase + (size_t)t * 64;
        *(float4*)(p)      = *(const float4*)(y);
        *(float4*)(p + 4)  = *(const float4*)(y + 4);
        *(float4*)(p + 32) = *(const float4*)(y + 8);
        *(float4*)(p + 36) = *(const float4*)(y + 12);
    };
    auto chainsum = [&](const float* y) {
        float s = ((y[0]+y[1])+(y[2]+y[3])) + ((y[4]+y[5])+(y[6]+y[7]))
                + ((y[8]+y[9])+(y[10]+y[11])) + ((y[12]+y[13])+(y[14]+y[15]));
        s += __shfl_xor(s, 16, 64);
        s += __shfl_xor(s, 32, 64);
        return s;
    };
    auto matstep = [&](const float* z, float* y) {
        short8 ah0, al0, ah1, al1;
        split8(z, ah0, al0);
        split8(z + 8, ah1, al1);
        f32x4 Dv[4];
        #pragma unroll
        for (int nt = 0; nt < 4; nt++) {
            f32x4 acc = {0.f, 0.f, 0.f, 0.f};
            acc = MFMA_BF16(ah0, Bh[nt][0], acc, 0, 0, 0);
            acc = MFMA_BF16(al0, Bh[nt][0], acc, 0, 0, 0);
            acc = MFMA_BF16(ah0, Bl[nt][0], acc, 0, 0, 0);
            acc = MFMA_BF16(ah1, Bh[nt][1], acc, 0, 0, 0);
            acc = MFMA_BF16(al1, Bh[nt][1], acc, 0, 0, 0);
            acc = MFMA_BF16(ah1, Bl[nt][1], acc, 0, 0, 0);
            Dv[nt] = acc;
        }
        #pragma unroll
        for (int r = 0; r < 4; r++) {
            lds[wrofs + r * 68]      = Dv[0][r];
            lds[wrofs + r * 68 + 16] = Dv[1][r];
            lds[wrofs + r * 68 + 32] = Dv[2][r];
            lds[wrofs + r * 68 + 48] = Dv[3][r];
        }
        __asm__ __volatile__("s_waitcnt lgkmcnt(0)" ::: "memory");
        *(float4*)(y)      = *(const float4*)&lds[rdofs];
        *(float4*)(y + 4)  = *(const float4*)&lds[rdofs + 4];
        *(float4*)(y + 8)  = *(const float4*)&lds[rdofs + 32];
        *(float4*)(y + 12) = *(const float4*)&lds[rdofs + 36];
        __asm__ __volatile__("s_waitcnt lgkmcnt(0)" ::: "memory");
    };

    if (isf) {
        const int wlo = ch * CL, te = wlo + CL - 1;
        int ts, nwarm;
        if (ch == 0) {
            float e[16], ip[16];
            loadE(0, e);
            const float* pp = initp + q * 8;
            *(float4*)(ip)      = *(const float4*)(pp);
            *(float4*)(ip + 4)  = *(const float4*)(pp + 4);
            *(float4*)(ip + 8)  = *(const float4*)(pp + 32);
            *(float4*)(ip + 12) = *(const float4*)(pp + 36);
            #pragma unroll
            for (int i = 0; i < 16; i++) w[i] = ip[i] * e[i];   // t=0: raw emission
            storeY(w, 0);
            float s = chainsum(w);
            rcpS = __builtin_amdgcn_rcpf(s);
            C = __log2f(s);
            ts = 1; nwarm = 0;
        } else {
            ts = wlo - 32; if (ts < 1) ts = 1;
            nwarm = wlo - ts;
            float e[16];
            loadE(ts - 1, e);
            #pragma unroll
            for (int i = 0; i < 16; i++) w[i] = e[i] + 1e-10f;  // proxy start
            float s = chainsum(w);
            rcpS = __builtin_amdgcn_rcpf(s);
            C = 0.f;
        }
        auto stepF = [&](int t, bool owned) {
            float e[16];
            loadE(t, e);                 // hidden behind matstep
            float y[16];
            matstep(w, y);
            float epsr = 1e-10f * rcpS;
            #pragma unroll
            for (int i = 0; i < 16; i++) y[i] *= fmaf(e[i], rcpS, epsr);
            float s = chainsum(y);
            if (owned) { C += __log2f(s); storeY(y, t); }
            rcpS = __builtin_amdgcn_rcpf(s);
            #pragma unroll
            for (int i = 0; i < 16; i++) w[i] = y[i];
        };
        for (int i = 0; i < nwarm; i++) stepF(ts + i, false);
        for (int t = wlo > 0 ? wlo : 1; t <= te; t++) stepF(t, true);
        if (q == 0) atomicAdd(&ll[b], C * 0.69314718056f);
    } else {
        const int tlo = ch * CL;
        const int whi = (ch == NCH - 1) ? T_ - 2 : tlo + CL - 1;
        int ts, nwarm;
        if (ch == NCH - 1) {
            float ones[16];
            #pragma unroll
            for (int i = 0; i < 16; i++) ones[i] = 1.f;
            storeY(ones, T_ - 1);
            float e[16];
            loadE(T_ - 1, e);
            #pragma unroll
            for (int i = 0; i < 16; i++) w[i] = e[i] + 1e-10f;  // w = beta*e at T-1
            rcpS = 1.f / 64.f;
            nwarm = 0; ts = T_ - 2;
        } else {
            ts = whi + 31; if (ts > T_ - 2) ts = T_ - 2;
            nwarm = ts - whi;
            float e[16];
            loadE(ts + 1, e);
            #pragma unroll
            for (int i = 0; i < 16; i++) w[i] = e[i] + 1e-10f;  // proxy beta=1
            rcpS = 1.f / 64.f;
        }
        auto stepB = [&](int t, bool owned) {
            float e[16];
            loadE(t, e);                 // e_t, consumed at end (hidden)
            float y[16];
            matstep(w, y);
            #pragma unroll
            for (int i = 0; i < 16; i++) y[i] *= rcpS;
            float s = chainsum(y);
            if (owned) storeY(y, t);
            rcpS = __builtin_amdgcn_rcpf(s);
            #pragma unroll
            for (int i = 0; i < 16; i++) w[i] = y[i] * (e[i] + 1e-10f);
        };
        for (int i = 0; i < nwarm; i++) stepB(ts - i, false);
        for (int t = whi; t >= tlo; t--) stepB(t, true);
    }
}

// ---------------- Kernel D: gamma (in-place over alpha in d_out) + marginals
__global__ __launch_bounds__(256) void gamma_k(const float* __restrict__ beta,
                                               float* __restrict__ out) {
    int wid = threadIdx.x >> 6, lane = threadIdx.x & 63;
    int b = blockIdx.x >> 4;
    int tile = blockIdx.x & 15;
    int t0 = tile * 256 + wid * 64;
    float macc = 0.f;
    size_t base = ((size_t)b * T_ + t0) * 64 + lane;
    for (int i = 0; i < 64; i++) {
        float a  = out[base + (size_t)i * 64];
        float be = beta[((size_t)b * T_ + t0 + i) * 64 + lane];
        float p = a * be;
        float s = rlane(wsum_dpp63(p), 63);
        float g = p * __builtin_amdgcn_rcpf(fmaxf(s, 1e-37f));
        out[base + (size_t)i * 64] = g;
        macc += g;
    }
    atomicAdd(&out[MARG_OFF + b * 64 + lane], macc * (1.0f / T_));
}

extern "C" void kernel_launch(void* const* d_in, const int* in_sizes, int n_in,
                              void* d_out, int out_size, void* d_ws, size_t ws_size,
                              hipStream_t stream) {
    (void)in_sizes; (void)n_in; (void)out_size; (void)ws_size;
    const float* obs    = (const float*)d_in[0];
    const float* W1     = (const float*)d_in[1];
    const float* b1     = (const float*)d_in[2];
    const float* W2     = (const float*)d_in[3];
    const float* b2     = (const float*)d_in[4];
    const float* W3     = (const float*)d_in[5];
    const float* b3     = (const float*)d_in[6];
    const float* LT     = (const float*)d_in[7];
    const float* lip    = (const float*)d_in[8];
    const float* logr   = (const float*)d_in[9];
    const float* logitp = (const float*)d_in[10];
    float* out = (float*)d_out;
    float* ws  = (float*)d_ws;

    hipLaunchKernelGGL(prep_k, dim3(8), dim3(256), 0, stream,
                       LT, lip, logr, logitp, W1, W2, W3, ws, out);
    hipLaunchKernelGGL(mlp_k, dim3(1024), dim3(256), 0, stream,
                       obs, (const unsigned short*)(ws + WSPLIT_OFF),
                       b1, b2, b3, ws + EM_OFF);
    hipLaunchKernelGGL(scan_k, dim3(4 * NCH), dim3(64), 0, stream,
                       ws + EM_OFF, ws + P_OFF, ws + PT_OFF, ws + INITP_OFF,
                       out + SP_OFF, ws + BETA_OFF, out + LL_OFF);
    hipLaunchKernelGGL(gamma_k, dim3(512), dim3(256), 0, stream, ws + BETA_OFF, out);
}